// Round 5
// baseline (666.113 us; speedup 1.0000x reference)
//
#include <hip/hip_runtime.h>
#include <stdint.h>
#include <stddef.h>

// SinkhornScorer fused kernel for MI355X (gfx950).
// One workgroup (256 threads) per batch element b:
//   phase 1+2: software-pipelined K-loop, 2 chunks deep in registers:
//     loads for chunk kc+2 are issued as soon as chunk kc's regs are consumed,
//     so each chunk pays ~1 amortized HBM latency instead of ~4-5 serialized
//     (round-4 post-mortem: VGPR=64 forced load-destination reuse -> serial
//      loads -> all resident waves stalled in lockstep, SIMDs ~72% idle).
//     bf16 LDS tiles are double-buffered -> ONE barrier per chunk (6 total),
//     MFMA(kc) overlaps staging of kc+1.
//   phase 3: Sinkhorn (20 iters) on wave ((b>>8)^b)&3 (XCD-stride-aware SIMD
//     spread), base-2 log domain, no-max LSE, C rows cached in VGPRs.
//   phase 4: Z write + <P,S> block reduction.
// launch_bounds(256,3): VGPR cap ~170 for the 2-deep pipeline (NO spill —
// watch WRITE_SIZE ~11 MB; round-1's cap-48 spill cost +280 MB scratch).
// LDS ~47 KB -> 3 blocks/CU.

typedef float  f4  __attribute__((ext_vector_type(4)));
typedef short  s8v __attribute__((ext_vector_type(8)));
typedef unsigned int u2v __attribute__((ext_vector_type(2)));

#define HD   768
#define MR   36          // rows (M == N == 36)
#define KC   128         // K-chunk
#define NCH  6           // 768/128
#define AS   136         // LDS row stride (bf16 elems) for A/B tiles
#define CS   44          // LDS row stride (floats) for C2/C2T
#define ITERS 20
#define LOG2E 1.4426950408889634f
#define LN2   0.6931471805599453f
#define L272  6.169925001442312f   // log2(72) = -norm_c in base-2
#define KC2   (10.0f*LOG2E)        // couplings scale: /REG then *log2e
#define NEGB  (-1.0e30f)

__device__ __forceinline__ uint32_t pkbf2(float a, float b) {
    // two fp32 -> packed bf16 (RNE)
    uint32_t ua = __float_as_uint(a), ub = __float_as_uint(b);
    ua += 0x7FFFu + ((ua >> 16) & 1u);
    ub += 0x7FFFu + ((ub >> 16) & 1u);
    return (ua >> 16) | (ub & 0xFFFF0000u);
}

// issue all 10 f4 loads of chunk KCI into register sets XS/YS (no waits here)
#define LOADCHUNK(KCI, XS, YS) {                                          \
    const int k0_ = (KCI) * KC;                                           \
    _Pragma("unroll")                                                     \
    for (int p = 0; p < 5; ++p) {                                         \
        if (p < 4 || t < 128) {                                           \
            const int row_ = (p < 4) ? (p * 8 + gg) : (32 + gg);          \
            XS[p] = *(const f4*)(xp + row_ * HD + k0_ + c4 * 4);          \
            YS[p] = *(const f4*)(yp + row_ * HD + k0_ + c4 * 4);          \
        }                                                                 \
    }                                                                     \
}

// consume chunk KCI from XS/YS: stats + bf16 pack + ds_write to buffer (KCI&1)
#define PROCCHUNK(KCI, XS, YS) {                                          \
    const int k0_ = (KCI) * KC;                                           \
    f4 gvv = *(const f4*)(LG + k0_ + c4 * 4);                             \
    f4 wvv = *(const f4*)(W  + k0_ + c4 * 4);                             \
    f4 gw  = gvv * wvv;                                                   \
    uint16_t* Alc = AB + ((KCI) & 1) * (72 * AS);                         \
    uint16_t* Btc = Alc + 36 * AS;                                        \
    _Pragma("unroll")                                                     \
    for (int p = 0; p < 5; ++p) {                                         \
        if (p < 4 || t < 128) {                                           \
            const int row_ = (p < 4) ? (p * 8 + gg) : (32 + gg);          \
            f4 xv = XS[p];                                                \
            sx[p][0] += (xv.x + xv.y) + (xv.z + xv.w);                    \
            sx[p][1] += xv.x*xv.x + xv.y*xv.y + xv.z*xv.z + xv.w*xv.w;    \
            sx[p][2] += xv.x*gw.x + xv.y*gw.y + xv.z*gw.z + xv.w*gw.w;    \
            u2v px; px.x = pkbf2(xv.x, xv.y); px.y = pkbf2(xv.z, xv.w);   \
            *(u2v*)&Alc[row_ * AS + c4 * 4] = px;                         \
            f4 yv = YS[p];                                                \
            sy[p][0] += (yv.x + yv.y) + (yv.z + yv.w);                    \
            sy[p][1] += yv.x*yv.x + yv.y*yv.y + yv.z*yv.z + yv.w*yv.w;    \
            sy[p][2] += yv.x*gw.x + yv.y*gw.y + yv.z*gw.z + yv.w*gw.w;    \
            u2v py; py.x = pkbf2(yv.x, yv.y); py.y = pkbf2(yv.z, yv.w);   \
            *(u2v*)&Btc[row_ * AS + c4 * 4] = py;                         \
        }                                                                 \
    }                                                                     \
}

#define MFMACHUNK(KCI) {                                                  \
    if (wv < 3) {                                                         \
        const uint16_t* Alc = AB + ((KCI) & 1) * (72 * AS);               \
        const uint16_t* Btc = Alc + 36 * AS;                              \
        _Pragma("unroll")                                                 \
        for (int ks = 0; ks < 4; ++ks) {                                  \
            s8v af = *(const s8v*)&Alc[rA + ks * 32];                     \
            s8v b0 = *(const s8v*)&Btc[rB0 + ks * 32];                    \
            acc[0] = __builtin_amdgcn_mfma_f32_16x16x32_bf16(af, b0, acc[0], 0, 0, 0); \
            s8v b1 = *(const s8v*)&Btc[rB1 + ks * 32];                    \
            acc[1] = __builtin_amdgcn_mfma_f32_16x16x32_bf16(af, b1, acc[1], 0, 0, 0); \
            s8v b2 = *(const s8v*)&Btc[rB2 + ks * 32];                    \
            acc[2] = __builtin_amdgcn_mfma_f32_16x16x32_bf16(af, b2, acc[2], 0, 0, 0); \
        }                                                                 \
    }                                                                     \
}

__global__ __launch_bounds__(256, 3) void sinkhorn_kernel(
    const float* __restrict__ X, const float* __restrict__ Y,
    const float* __restrict__ LG, const float* __restrict__ LB,
    const float* __restrict__ W,  const float* __restrict__ BL,
    float* __restrict__ OUT, int NB)
{
    // two bf16 tile buffers (A rows 0..35 + B rows 0..35 each)
    __shared__ __align__(16) uint16_t AB[144 * AS];  // 39168 B; buf0 later reused as C2T
    __shared__ __align__(16) float C2 [37 * CS];     // couplings * log2e, cols 37..39 = -1e30 pad
    __shared__ __align__(16) float u_l[40];
    __shared__ __align__(16) float v_l[40];
    __shared__ float stx[MR * 3], sty[MR * 3];       // per-row {Sx, Sxx, Sxw}
    __shared__ float rnx[MR], rny[MR];               // 1/||row||
    __shared__ float s_gw, s_bw, red[4];

    float* C2T = (float*)AB;                         // valid only after last buf0 MFMA

    const int t  = threadIdx.x;
    const int b  = blockIdx.x;
    const int wv = t >> 6, ln = t & 63;
    const int c4 = t & 31, gg = t >> 5;

    // ---- one-time inits ----
    if (t < 40) { u_l[t] = 0.0f; v_l[t] = 0.0f; }
    if (t < 37) {
        C2[t * CS + 37] = NEGB; C2[t * CS + 38] = NEGB; C2[t * CS + 39] = NEGB;
    }
    if (wv == 3) {  // Sgw = sum g*w, Sbw = sum b*w (wave 3, once)
        float a = 0.0f, c = 0.0f;
        for (int q = 0; q < 12; ++q) {
            int h = ln + 64 * q;
            float wval = W[h];
            a += LG[h] * wval; c += LB[h] * wval;
        }
        for (int o = 32; o > 0; o >>= 1) { a += __shfl_down(a, o); c += __shfl_down(c, o); }
        if (ln == 0) { s_gw = a; s_bw = c; }
    }

    float sx[5][3], sy[5][3];
    #pragma unroll
    for (int p = 0; p < 5; ++p)
        #pragma unroll
        for (int s = 0; s < 3; ++s) { sx[p][s] = 0.0f; sy[p][s] = 0.0f; }

    f4 acc[3];
    #pragma unroll
    for (int i = 0; i < 3; ++i) acc[i] = (f4){0.0f, 0.0f, 0.0f, 0.0f};

    const float* xp = X + (size_t)b * (MR * HD);
    const float* yp = Y + (size_t)b * (MR * HD);

    const int frow = ln & 15, fq = ln >> 4;          // MFMA fragment row / k-quad
    // clamped fragment bases: rows >=36 read row 35 (their outputs are discarded)
    const int arR = wv * 16 + frow;
    const int rA  = ((arR < MR) ? arR : (MR - 1)) * AS + fq * 8;   // waves 0..2
    const int rB0 = (frow)      * AS + fq * 8;
    const int rB1 = (16 + frow) * AS + fq * 8;
    const int bt2 = 32 + frow;
    const int rB2 = ((bt2 < MR) ? bt2 : (MR - 1)) * AS + fq * 8;

    // ---- phase 1+2: 2-deep pipelined K-loop, double-buffered LDS ----
    f4 xA[5], yA[5], xB[5], yB[5];
    LOADCHUNK(0, xA, yA);
    LOADCHUNK(1, xB, yB);
    #pragma unroll
    for (int kk = 0; kk < 3; ++kk) {
        // even chunk 2kk (buffer 0)
        PROCCHUNK(2 * kk, xA, yA);
        if (2 * kk + 2 < NCH) LOADCHUNK(2 * kk + 2, xA, yA);
        __syncthreads();                      // buf0 staged by all waves
        MFMACHUNK(2 * kk);
        // odd chunk 2kk+1 (buffer 1) — writes to buf1 race-free vs buf0 reads
        PROCCHUNK(2 * kk + 1, xB, yB);
        if (2 * kk + 3 < NCH) LOADCHUNK(2 * kk + 3, xB, yB);
        __syncthreads();                      // buf1 staged by all waves
        MFMACHUNK(2 * kk + 1);
    }

    // ---- stats reduction: 32-lane groups own fixed rows (shuffles only) ----
    #pragma unroll
    for (int p = 0; p < 5; ++p) {
        const int row = (p < 4) ? (p * 8 + gg) : (32 + gg);
        #pragma unroll
        for (int s = 0; s < 3; ++s) {
            float a = sx[p][s], c = sy[p][s];
            for (int o = 16; o > 0; o >>= 1) { a += __shfl_down(a, o, 32); c += __shfl_down(c, o, 32); }
            if ((t & 31) == 0 && row < MR) { stx[row * 3 + s] = a; sty[row * 3 + s] = c; }
        }
    }
    __syncthreads();   // after this: all MFMA done -> buf0 dead -> C2T may go live

    // ---- derived per-row: 1/norm, dustbin scores (LayerNorm -> linear -> tanh) ----
    {
        const float blin = BL[0];
        if (t < MR) {
            float Sx = stx[t * 3], Sxx = stx[t * 3 + 1], Sxw = stx[t * 3 + 2];
            rnx[t] = __builtin_amdgcn_rsqf(Sxx);
            float mu  = Sx * (1.0f / HD);
            float var = Sxx * (1.0f / HD) - mu * mu;
            float rsd = __builtin_amdgcn_rsqf(var + 1e-5f);
            float lin = (Sxw - mu * s_gw) * rsd + s_bw + blin;
            float e   = __builtin_amdgcn_exp2f(2.0f * LOG2E * lin);
            float th  = (e - 1.0f) / (e + 1.0f);
            C2 [t * CS + 36] = th * KC2;
            C2T[36 * CS + t] = th * KC2;
        } else if (t >= 64 && t < 64 + MR) {
            int j = t - 64;
            float Sy = sty[j * 3], Syy = sty[j * 3 + 1], Syw = sty[j * 3 + 2];
            rny[j] = __builtin_amdgcn_rsqf(Syy);
            float mu  = Sy * (1.0f / HD);
            float var = Syy * (1.0f / HD) - mu * mu;
            float rsd = __builtin_amdgcn_rsqf(var + 1e-5f);
            float lin = (Syw - mu * s_gw) * rsd + s_bw + blin;
            float e   = __builtin_amdgcn_exp2f(2.0f * LOG2E * lin);
            float th  = (e - 1.0f) / (e + 1.0f);
            C2 [36 * CS + j] = th * KC2;
            C2T[j * CS + 36] = th * KC2;
        } else if (t == 128) {
            C2 [36 * CS + 36] = -100.0f * KC2;   // ALPHA_BOTH/REG in base-2
            C2T[36 * CS + 36] = -100.0f * KC2;
        } else if (t >= 192 && t < 192 + 37) {
            int r = t - 192;                     // C2T pad cols (aliased space)
            C2T[r * CS + 37] = NEGB; C2T[r * CS + 38] = NEGB; C2T[r * CS + 39] = NEGB;
        }
    }
    __syncthreads();

    // ---- scores -> couplings (base-2) into C2 and C2T ----
    if (wv < 3) {
        #pragma unroll
        for (int tn = 0; tn < 3; ++tn) {
            #pragma unroll
            for (int r = 0; r < 4; ++r) {
                int i = wv * 16 + fq * 4 + r;   // A-operand index (x row)
                int j = tn * 16 + frow;         // B-operand index (y row)
                if (i < MR && j < MR) {
                    float v = acc[tn][r] * rnx[i] * rny[j] * KC2;
                    C2 [i * CS + j] = v;
                    C2T[j * CS + i] = v;
                }
            }
        }
    }
    __syncthreads();

    // ---- Sinkhorn: wave ((b>>8)^b)&3, base-2, no-max LSE, reg-cached C ----
    const int sw = ((b >> 8) ^ b) & 3;
    if (wv == sw && ln < 37) {
        const int i = ln;
        const float lmu = (i < MR) ? -L272 : -1.0f;  // log2 marginals (mu == nu for M==N)
        f4 cr[10], ct[10];                            // C rows cached in VGPRs (invariant)
        #pragma unroll
        for (int jj = 0; jj < 10; ++jj) {
            cr[jj] = *(const f4*)(&C2 [i * CS + jj * 4]);
            ct[jj] = *(const f4*)(&C2T[i * CS + jj * 4]);
        }
        for (int it = 0; it < ITERS; ++it) {
            {   // u-update: LSE over columns j of (C + v); no max (args bounded, pads -> 0)
                f4 ea = (f4){0.0f,0.0f,0.0f,0.0f}, eb = (f4){0.0f,0.0f,0.0f,0.0f};
                #pragma unroll
                for (int jj = 0; jj < 10; ++jj) {
                    f4 sv = cr[jj] + *(const f4*)(&v_l[jj * 4]);
                    f4 ev;
                    ev.x = __builtin_amdgcn_exp2f(sv.x);
                    ev.y = __builtin_amdgcn_exp2f(sv.y);
                    ev.z = __builtin_amdgcn_exp2f(sv.z);
                    ev.w = __builtin_amdgcn_exp2f(sv.w);
                    if (jj & 1) eb += ev; else ea += ev;
                }
                f4 et = ea + eb;
                float ss = (et.x + et.y) + (et.z + et.w);
                u_l[i] = lmu - __builtin_amdgcn_logf(ss);
            }
            {   // v-update: LSE over rows i of (C + u) == over cols of C^T
                f4 ea = (f4){0.0f,0.0f,0.0f,0.0f}, eb = (f4){0.0f,0.0f,0.0f,0.0f};
                #pragma unroll
                for (int jj = 0; jj < 10; ++jj) {
                    f4 sv = ct[jj] + *(const f4*)(&u_l[jj * 4]);
                    f4 ev;
                    ev.x = __builtin_amdgcn_exp2f(sv.x);
                    ev.y = __builtin_amdgcn_exp2f(sv.y);
                    ev.z = __builtin_amdgcn_exp2f(sv.z);
                    ev.w = __builtin_amdgcn_exp2f(sv.w);
                    if (jj & 1) eb += ev; else ea += ev;
                }
                f4 et = ea + eb;
                float ss = (et.x + et.y) + (et.z + et.w);
                v_l[i] = lmu - __builtin_amdgcn_logf(ss);
            }
        }
    }
    __syncthreads();

    // ---- epilogue: Z write + total = <exp(Z), scores>/TEMP ----
    float tot = 0.0f;
    const size_t ob = (size_t)b * 1369;
    for (int e = t; e < 1369; e += 256) {
        int i = e / 37, j = e - i * 37;
        float c2v = C2[i * CS + j];
        float z2  = c2v + u_l[i] + v_l[j] + L272;   // - norm_c == + log2(72) in base-2
        OUT[ob + e] = z2 * LN2;
        if (i < MR && j < MR)
            tot += __builtin_amdgcn_exp2f(z2) * (c2v * (0.1f * LN2));  // scores = C2 * REG * ln2
    }
    for (int o = 32; o > 0; o >>= 1) tot += __shfl_down(tot, o);
    if (ln == 0) red[wv] = tot;
    __syncthreads();
    if (t == 0) OUT[(size_t)NB * 1369 + b] = (red[0] + red[1] + red[2] + red[3]) * 10.0f;  // /TEMP
}

extern "C" void kernel_launch(void* const* d_in, const int* in_sizes, int n_in,
                              void* d_out, int out_size, void* d_ws, size_t ws_size,
                              hipStream_t stream) {
    const float* X  = (const float*)d_in[0];
    const float* Y  = (const float*)d_in[1];
    const float* LG = (const float*)d_in[2];
    const float* LB = (const float*)d_in[3];
    const float* W  = (const float*)d_in[4];
    const float* BL = (const float*)d_in[5];
    const int NB = in_sizes[0] / (MR * HD);   // 2048
    hipLaunchKernelGGL(sinkhorn_kernel, dim3(NB), dim3(256), 0, stream,
                       X, Y, LG, LB, W, BL, (float*)d_out, NB);
}

// Round 6
// 494.960 us; speedup vs baseline: 1.3458x; 1.3458x over previous
//
#include <hip/hip_runtime.h>
#include <stdint.h>
#include <stddef.h>

// SinkhornScorer for MI355X (gfx950), TWO-KERNEL structure.
//
// Round-5 post-mortem: monolithic kernel couples a BW phase (stream 452 MB)
// to a latency phase (1-wave Sinkhorn): a block holds its CU slot through the
// Sinkhorn tail (3 of 4 waves idle), so streaming blocks can't turn over, and
// register-pipeline attempts spilled (compiler kept VGPR=64/84 and sent f4
// arrays to scratch: WRITE_SIZE 11->323 MB).
//
// Kernel A (score_kernel, 2048 x 256thr): stream x,y once (loads-first, named
//   f4 vars, 12 loads in flight, sched_group_barrier pin), stats via shuffles,
//   MFMA 16x16x32 bf16 scores, dustbin row/col; writes RAW base-2 couplings
//   (37x37) into OUT's Z region (scratch; overwritten by kernel B).
// Kernel B (sinkhorn_kernel, 2048 x 64thr, 1 wave): loads C from OUT into LDS
//   (+transpose), 20 Sinkhorn iters with C rows REALLY cached in VGPRs
//   (launch_bounds(64,2) -> cap 256 regs; monolithic kernel's 64-reg budget
//   silently rematerialized the "cached" rows as LDS reads), overwrites OUT
//   with Z and writes totals. 8 one-wave blocks/CU = 2 Sinkhorn waves/SIMD.

typedef float  f4  __attribute__((ext_vector_type(4)));
typedef short  s8v __attribute__((ext_vector_type(8)));
typedef unsigned int u2v __attribute__((ext_vector_type(2)));

#define HD   768
#define MR   36          // rows (M == N == 36)
#define KC   128         // K-chunk
#define NCH  6           // 768/128
#define AS   136         // LDS row stride (bf16 elems) for A/B tiles
#define CS   44          // LDS row stride (floats) for C2/C2T
#define ITERS 20
#define LOG2E 1.4426950408889634f
#define LN2   0.6931471805599453f
#define L272  6.169925001442312f   // log2(72) = -norm_c in base-2
#define KC2   (10.0f*LOG2E)        // couplings scale: /REG then *log2e
#define NEGB  (-1.0e30f)

__device__ __forceinline__ uint32_t pkbf2(float a, float b) {
    // two fp32 -> packed bf16 (RNE)
    uint32_t ua = __float_as_uint(a), ub = __float_as_uint(b);
    ua += 0x7FFFu + ((ua >> 16) & 1u);
    ub += 0x7FFFu + ((ub >> 16) & 1u);
    return (ua >> 16) | (ub & 0xFFFF0000u);
}

// stats + bf16-pack + LDS store for one (row, xv, yv); P is a literal index.
#define STEP(P, XV, YV, ROW) {                                             \
    sx[P][0] += (XV.x + XV.y) + (XV.z + XV.w);                             \
    sx[P][1] += XV.x*XV.x + XV.y*XV.y + XV.z*XV.z + XV.w*XV.w;             \
    sx[P][2] += XV.x*gw.x + XV.y*gw.y + XV.z*gw.z + XV.w*gw.w;             \
    u2v px; px.x = pkbf2(XV.x, XV.y); px.y = pkbf2(XV.z, XV.w);            \
    *(u2v*)&Al[(ROW) * AS + c4 * 4] = px;                                  \
    sy[P][0] += (YV.x + YV.y) + (YV.z + YV.w);                             \
    sy[P][1] += YV.x*YV.x + YV.y*YV.y + YV.z*YV.z + YV.w*YV.w;             \
    sy[P][2] += YV.x*gw.x + YV.y*gw.y + YV.z*gw.z + YV.w*gw.w;             \
    u2v py; py.x = pkbf2(YV.x, YV.y); py.y = pkbf2(YV.z, YV.w);            \
    *(u2v*)&Bt[(ROW) * AS + c4 * 4] = py;                                  \
}

__global__ __launch_bounds__(256, 4) void score_kernel(
    const float* __restrict__ X, const float* __restrict__ Y,
    const float* __restrict__ LG, const float* __restrict__ LB,
    const float* __restrict__ W,  const float* __restrict__ BL,
    float* __restrict__ OUT, int NB)
{
    __shared__ __align__(16) uint16_t AB[72 * AS];   // bf16 tiles (A rows 0..35, B rows 0..35)
    __shared__ __align__(16) float C2 [37 * CS];     // couplings * log2e (base-2)
    __shared__ float stx[MR * 3], sty[MR * 3];       // per-row {Sx, Sxx, Sxw}
    __shared__ float rnx[MR], rny[MR];               // 1/||row||
    __shared__ float s_gw, s_bw;

    uint16_t* Al = AB;
    uint16_t* Bt = AB + 36 * AS;

    const int t  = threadIdx.x;
    const int b  = blockIdx.x;
    const int wv = t >> 6, ln = t & 63;
    const int c4 = t & 31, gg = t >> 5;

    if (wv == 3) {  // Sgw = sum g*w, Sbw = sum b*w (wave 3, once)
        float a = 0.0f, c = 0.0f;
        for (int q = 0; q < 12; ++q) {
            int h = ln + 64 * q;
            float wval = W[h];
            a += LG[h] * wval; c += LB[h] * wval;
        }
        for (int o = 32; o > 0; o >>= 1) { a += __shfl_down(a, o); c += __shfl_down(c, o); }
        if (ln == 0) { s_gw = a; s_bw = c; }
    }

    float sx[5][3], sy[5][3];
    #pragma unroll
    for (int p = 0; p < 5; ++p)
        #pragma unroll
        for (int s = 0; s < 3; ++s) { sx[p][s] = 0.0f; sy[p][s] = 0.0f; }

    f4 acc[3];
    #pragma unroll
    for (int i = 0; i < 3; ++i) acc[i] = (f4){0.0f, 0.0f, 0.0f, 0.0f};

    const float* xb = X + (size_t)b * (MR * HD);
    const float* yb = Y + (size_t)b * (MR * HD);

    // row assignments: p=0..3 -> p*8+gg (rows 0..31); p=4 -> 32+gg for t<128,
    // clamped to 35 for t>=128 (duplicate same-value LDS writes; stats for
    // clamped lanes map to rows>=36 and are discarded at the reduce store).
    const int r0 = gg, r1 = 8 + gg, r2 = 16 + gg, r3 = 24 + gg;
    const int r4 = (t < 128) ? (32 + gg) : 35;

    const int frow = ln & 15, fq = ln >> 4;          // MFMA fragment row / k-quad
    const int arR = wv * 16 + frow;
    const int rA  = ((arR < MR) ? arR : (MR - 1)) * AS + fq * 8;   // waves 0..2
    const int rB0 = (frow)      * AS + fq * 8;
    const int rB1 = (16 + frow) * AS + fq * 8;
    const int bt2 = 32 + frow;
    const int rB2 = ((bt2 < MR) ? bt2 : (MR - 1)) * AS + fq * 8;

    // ---- streaming K-loop: all 12 chunk loads issued back-to-back ----
    for (int kc = 0; kc < NCH; ++kc) {
        const int k0 = kc * KC;
        const float* xr = xb + k0 + c4 * 4;
        const float* yr = yb + k0 + c4 * 4;
        f4 gv   = *(const f4*)(LG + k0 + c4 * 4);
        f4 wvec = *(const f4*)(W  + k0 + c4 * 4);
        f4 x0 = *(const f4*)(xr + r0 * HD);
        f4 y0 = *(const f4*)(yr + r0 * HD);
        f4 x1 = *(const f4*)(xr + r1 * HD);
        f4 y1 = *(const f4*)(yr + r1 * HD);
        f4 x2 = *(const f4*)(xr + r2 * HD);
        f4 y2 = *(const f4*)(yr + r2 * HD);
        f4 x3 = *(const f4*)(xr + r3 * HD);
        f4 y3 = *(const f4*)(yr + r3 * HD);
        f4 x4 = *(const f4*)(xr + r4 * HD);
        f4 y4 = *(const f4*)(yr + r4 * HD);
        // pin: schedule the 12 VMEM reads of this chunk before any consumer
        __builtin_amdgcn_sched_group_barrier(0x20, 12, 0);
        f4 gw = gv * wvec;
        STEP(0, x0, y0, r0);
        STEP(1, x1, y1, r1);
        STEP(2, x2, y2, r2);
        STEP(3, x3, y3, r3);
        STEP(4, x4, y4, r4);
        __syncthreads();
        if (wv < 3) {
            #pragma unroll
            for (int ks = 0; ks < 4; ++ks) {
                s8v af = *(const s8v*)&Al[rA + ks * 32];
                s8v b0 = *(const s8v*)&Bt[rB0 + ks * 32];
                acc[0] = __builtin_amdgcn_mfma_f32_16x16x32_bf16(af, b0, acc[0], 0, 0, 0);
                s8v b1 = *(const s8v*)&Bt[rB1 + ks * 32];
                acc[1] = __builtin_amdgcn_mfma_f32_16x16x32_bf16(af, b1, acc[1], 0, 0, 0);
                s8v b2 = *(const s8v*)&Bt[rB2 + ks * 32];
                acc[2] = __builtin_amdgcn_mfma_f32_16x16x32_bf16(af, b2, acc[2], 0, 0, 0);
            }
        }
        __syncthreads();
    }

    // ---- stats reduction: 32-lane groups own fixed rows ----
    #pragma unroll
    for (int p = 0; p < 5; ++p) {
        const int row = (p < 4) ? (p * 8 + gg) : (32 + gg);  // >=36 discarded
        #pragma unroll
        for (int s = 0; s < 3; ++s) {
            float a = sx[p][s], c = sy[p][s];
            for (int o = 16; o > 0; o >>= 1) { a += __shfl_down(a, o, 32); c += __shfl_down(c, o, 32); }
            if ((t & 31) == 0 && row < MR) { stx[row * 3 + s] = a; sty[row * 3 + s] = c; }
        }
    }
    __syncthreads();

    // ---- derived per-row: 1/norm, dustbin scores (LayerNorm -> linear -> tanh) ----
    {
        const float blin = BL[0];
        if (t < MR) {
            float Sx = stx[t * 3], Sxx = stx[t * 3 + 1], Sxw = stx[t * 3 + 2];
            rnx[t] = __builtin_amdgcn_rsqf(Sxx);
            float mu  = Sx * (1.0f / HD);
            float var = Sxx * (1.0f / HD) - mu * mu;
            float rsd = __builtin_amdgcn_rsqf(var + 1e-5f);
            float lin = (Sxw - mu * s_gw) * rsd + s_bw + blin;
            float e   = __builtin_amdgcn_exp2f(2.0f * LOG2E * lin);
            float th  = (e - 1.0f) / (e + 1.0f);
            C2[t * CS + 36] = th * KC2;
        } else if (t >= 64 && t < 64 + MR) {
            int j = t - 64;
            float Sy = sty[j * 3], Syy = sty[j * 3 + 1], Syw = sty[j * 3 + 2];
            rny[j] = __builtin_amdgcn_rsqf(Syy);
            float mu  = Sy * (1.0f / HD);
            float var = Syy * (1.0f / HD) - mu * mu;
            float rsd = __builtin_amdgcn_rsqf(var + 1e-5f);
            float lin = (Syw - mu * s_gw) * rsd + s_bw + blin;
            float e   = __builtin_amdgcn_exp2f(2.0f * LOG2E * lin);
            float th  = (e - 1.0f) / (e + 1.0f);
            C2[36 * CS + j] = th * KC2;
        } else if (t == 128) {
            C2[36 * CS + 36] = -100.0f * KC2;   // ALPHA_BOTH/REG in base-2
        }
    }
    __syncthreads();

    // ---- scores -> couplings (base-2) into C2 ----
    if (wv < 3) {
        #pragma unroll
        for (int tn = 0; tn < 3; ++tn) {
            #pragma unroll
            for (int r = 0; r < 4; ++r) {
                int i = wv * 16 + fq * 4 + r;   // A-operand index (x row)
                int j = tn * 16 + frow;         // B-operand index (y row)
                if (i < MR && j < MR)
                    C2[i * CS + j] = acc[tn][r] * rnx[i] * rny[j] * KC2;
            }
        }
    }
    __syncthreads();

    // ---- write raw couplings (base-2) to OUT Z-region (scratch for kernel B) ----
    const size_t ob = (size_t)b * 1369;
    for (int e = t; e < 1369; e += 256) {
        int i = e / 37, j = e - i * 37;
        OUT[ob + e] = C2[i * CS + j];
    }
}

__global__ __launch_bounds__(64, 2) void sinkhorn_kernel(
    float* __restrict__ OUT, int NB)
{
    __shared__ __align__(16) float C2 [37 * CS];
    __shared__ __align__(16) float C2T[37 * CS];
    __shared__ __align__(16) float u_l[40];
    __shared__ __align__(16) float v_l[40];

    const int ln = threadIdx.x;
    const int b  = blockIdx.x;
    const size_t ob = (size_t)b * 1369;

    if (ln < 40) { u_l[ln] = 0.0f; v_l[ln] = 0.0f; }
    if (ln < 37) {
        C2 [ln * CS + 37] = NEGB; C2 [ln * CS + 38] = NEGB; C2 [ln * CS + 39] = NEGB;
        C2T[ln * CS + 37] = NEGB; C2T[ln * CS + 38] = NEGB; C2T[ln * CS + 39] = NEGB;
    }
    for (int e = ln; e < 1369; e += 64) {          // 22 iters: load C, build C and C^T
        int i = e / 37, j = e - i * 37;
        float c = OUT[ob + e];
        C2 [i * CS + j] = c;
        C2T[j * CS + i] = c;
    }
    __syncthreads();

    // ---- Sinkhorn: 20 iters, base-2 log domain, no-max LSE, C rows in VGPRs ----
    if (ln < 37) {
        const int i = ln;
        const float lmu = (i < MR) ? -L272 : -1.0f;  // log2 marginals (mu == nu, M==N)
        f4 cr[10], ct[10];                            // REALLY cached: cap 256 VGPR here
        #pragma unroll
        for (int jj = 0; jj < 10; ++jj) {
            cr[jj] = *(const f4*)(&C2 [i * CS + jj * 4]);
            ct[jj] = *(const f4*)(&C2T[i * CS + jj * 4]);
        }
        for (int it = 0; it < ITERS; ++it) {
            {   // u-update: LSE over columns j of (C + v); pads (-1e30) -> exp2 = 0
                f4 ea = (f4){0.0f,0.0f,0.0f,0.0f}, eb = (f4){0.0f,0.0f,0.0f,0.0f};
                #pragma unroll
                for (int jj = 0; jj < 10; ++jj) {
                    f4 sv = cr[jj] + *(const f4*)(&v_l[jj * 4]);
                    f4 ev;
                    ev.x = __builtin_amdgcn_exp2f(sv.x);
                    ev.y = __builtin_amdgcn_exp2f(sv.y);
                    ev.z = __builtin_amdgcn_exp2f(sv.z);
                    ev.w = __builtin_amdgcn_exp2f(sv.w);
                    if (jj & 1) eb += ev; else ea += ev;
                }
                f4 et = ea + eb;
                float ss = (et.x + et.y) + (et.z + et.w);
                u_l[i] = lmu - __builtin_amdgcn_logf(ss);
            }
            {   // v-update: LSE over rows i of (C + u) == over cols of C^T
                f4 ea = (f4){0.0f,0.0f,0.0f,0.0f}, eb = (f4){0.0f,0.0f,0.0f,0.0f};
                #pragma unroll
                for (int jj = 0; jj < 10; ++jj) {
                    f4 sv = ct[jj] + *(const f4*)(&u_l[jj * 4]);
                    f4 ev;
                    ev.x = __builtin_amdgcn_exp2f(sv.x);
                    ev.y = __builtin_amdgcn_exp2f(sv.y);
                    ev.z = __builtin_amdgcn_exp2f(sv.z);
                    ev.w = __builtin_amdgcn_exp2f(sv.w);
                    if (jj & 1) eb += ev; else ea += ev;
                }
                f4 et = ea + eb;
                float ss = (et.x + et.y) + (et.z + et.w);
                v_l[i] = lmu - __builtin_amdgcn_logf(ss);
            }
        }
    }
    __syncthreads();

    // ---- epilogue: Z write (overwrites couplings) + total = <exp(Z), scores>/TEMP ----
    float tot = 0.0f;
    for (int e = ln; e < 1369; e += 64) {
        int i = e / 37, j = e - i * 37;
        float c2v = C2[i * CS + j];
        float z2  = c2v + u_l[i] + v_l[j] + L272;   // - norm_c == + log2(72) in base-2
        OUT[ob + e] = z2 * LN2;
        if (i < MR && j < MR)
            tot += __builtin_amdgcn_exp2f(z2) * (c2v * (0.1f * LN2));  // scores = C2*REG*ln2
    }
    for (int o = 32; o > 0; o >>= 1) tot += __shfl_down(tot, o);
    if (ln == 0) OUT[(size_t)NB * 1369 + b] = tot * 10.0f;             // /TEMP
}

extern "C" void kernel_launch(void* const* d_in, const int* in_sizes, int n_in,
                              void* d_out, int out_size, void* d_ws, size_t ws_size,
                              hipStream_t stream) {
    const float* X  = (const float*)d_in[0];
    const float* Y  = (const float*)d_in[1];
    const float* LG = (const float*)d_in[2];
    const float* LB = (const float*)d_in[3];
    const float* W  = (const float*)d_in[4];
    const float* BL = (const float*)d_in[5];
    const int NB = in_sizes[0] / (MR * HD);   // 2048
    hipLaunchKernelGGL(score_kernel, dim3(NB), dim3(256), 0, stream,
                       X, Y, LG, LB, W, BL, (float*)d_out, NB);
    hipLaunchKernelGGL(sinkhorn_kernel, dim3(NB), dim3(64), 0, stream,
                       (float*)d_out, NB);
}